// Round 1
// 503.666 us; speedup vs baseline: 1.3606x; 1.3606x over previous
//
#include <hip/hip_runtime.h>

#define Tdim 1024
#define Ndim 64
#define FSZ (8 * 1024 * 64 * 8)

typedef unsigned uint2v __attribute__((ext_vector_type(2)));

// v + dpp(v) at VALU latency. ctrl: 0xB1=quad_perm[1,0,3,2](xor1),
// 0x4E=quad_perm[2,3,0,1](xor2), 0x141=row_half_mirror(xor7),
// 0x128=row_ror:8(xor8).
#define DPPADD(v, ctrl) ((v) + __int_as_float(__builtin_amdgcn_update_dpp( \
    0, __float_as_int(v), ctrl, 0xF, 0xF, false)))

__device__ __forceinline__ float swap_add16(float v) {  // + value from lane^16
  unsigned u = __float_as_uint(v);
  uint2v r = __builtin_amdgcn_permlane16_swap(u, u, false, false);
  return __uint_as_float(r[0]) + __uint_as_float(r[1]);
}
__device__ __forceinline__ float swap_add32(float v) {  // + value from lane^32
  unsigned u = __float_as_uint(v);
  uint2v r = __builtin_amdgcn_permlane32_swap(u, u, false, false);
  return __uint_as_float(r[0]) + __uint_as_float(r[1]);
}

// sum over lane bits {0,1,2}: xor1, xor2, then xor7 (== xor4 after bits 0,1 summed)
#define SUM_LO3(v) { v = DPPADD(v, 0xB1); v = DPPADD(v, 0x4E); v = DPPADD(v, 0x141); }
// sum over lane bits {3,4,5}: xor8 (row_ror:8), xor16, xor32 (permlane swaps)
#define SUM_HI3(v) { v = DPPADD(v, 0x128); v = swap_add16(v); v = swap_add32(v); }

// ---------------- kernel 1: forward + beta recursions ----------------
// One wave per chain. lane = x*8+y. Probability-domain state, alternating
// index layout (even s: normal A load, LO3 reduce; odd s: transposed A load,
// HI3 reduce) -> no transpose shuffle in the chain. All cross-lane ops are
// DPP/permlane (VALU pipe) -> per-step chain = mul, 3 dpp-adds, mul.
// eb (emission factors) loaded directly with the right index role and exp'd
// in the prefetch phase: no bpermute anywhere in the recursion.

__device__ __forceinline__ void fwd_load(const float* __restrict__ a_base,
                                         const float* __restrict__ b_base,
                                         int t0, int lane, int tr, int x, int y,
                                         float (&ea)[16], float (&eb)[16]) {
#pragma unroll
  for (int s = 0; s < 16; ++s) {
    int t = t0 + s; if (t > Tdim - 1) t = Tdim - 1;
    ea[s] = __expf(a_base[(size_t)t * (Ndim * 64) + ((s & 1) ? tr : lane)]);
    eb[s] = __expf(b_base[(size_t)t * (Ndim * 8) + ((s & 1) ? y : x)]);
  }
}

__device__ __forceinline__ void fwd_compute(int t0, int x, int y,
                                            const float (&ea)[16], const float (&eb)[16],
                                            float& q, float& sc,
                                            float* __restrict__ f_base) {
#pragma unroll
  for (int s = 0; s < 16; ++s) {
    int t = t0 + s;
    if (t < Tdim) {
      int oidx = (s & 1) ? y : x;                       // output state index role
      float v = ea[s] * q;                              // CHAIN
      if (!(s & 1)) { SUM_LO3(v); } else { SUM_HI3(v); }  // CHAIN: sum over j (VALU)
      float S = v * (eb[s] * sc);                       // CHAIN (eb*sc off-chain)
      q = S;
      float T = S;                                      // norm path (parallel)
      if (!(s & 1)) { SUM_HI3(T); } else { SUM_LO3(T); }
      sc = __builtin_amdgcn_rcpf(T);                    // approx ok: scale cancels
      float la = __logf(S) - __logf(T);                 // normalized alpha
      if ((((s & 1) ? x : y)) == 0) f_base[(size_t)t * (Ndim * 8) + oidx] = la;
    }
  }
}

// beta: u_i ~ e^{beta_tau[i] + b_tau[i]} (scaled). r_j = sum_i e^{a_tau[i,j]} u_i.
__device__ __forceinline__ void bwd_load(const float* __restrict__ a_base,
                                         const float* __restrict__ b_base,
                                         int t0, int lane, int tr, int x, int y,
                                         float (&ea)[16], float (&eb)[16]) {
#pragma unroll
  for (int s = 0; s < 16; ++s) {
    int t = t0 - s; if (t < 0) t = 0;
    ea[s] = __expf(a_base[(size_t)t * (Ndim * 64) + ((s & 1) ? tr : lane)]);
    int tb = t0 - 1 - s; if (tb < 0) tb = 0;            // b at time tau-1
    eb[s] = __expf(b_base[(size_t)tb * (Ndim * 8) + ((s & 1) ? x : y)]);
  }
}

__device__ __forceinline__ void bwd_compute(int t0, int x, int y,
                                            const float (&ea)[16], const float (&eb)[16],
                                            float& u, float& sc,
                                            float* __restrict__ bo) {
#pragma unroll
  for (int s = 0; s < 16; ++s) {
    int tau = t0 - s;
    if (tau >= 1) {
      float v = ea[s] * u;                              // CHAIN
      if (!(s & 1)) { SUM_HI3(v); } else { SUM_LO3(v); }  // CHAIN: sum over i
      int oidx = (s & 1) ? x : y;                       // r's index role
      float unew = (eb[s] * sc) * v;                    // CHAIN tail
      float W = v;                                      // norm path (parallel)
      if (!(s & 1)) { SUM_LO3(W); } else { SUM_HI3(W); }
      float lb = __logf(v) - __logf(W);
      if ((((s & 1) ? y : x)) == 0) bo[(size_t)(tau - 1) * (Ndim * 8) + oidx] = lb;
      u = unew;
      sc = __builtin_amdgcn_rcpf(W);
    }
  }
}

__global__ __launch_bounds__(64) void chains_kernel(const float* __restrict__ A,
                                                    const float* __restrict__ Bm,
                                                    const float* __restrict__ Z1,
                                                    float* __restrict__ Fout,
                                                    float* __restrict__ Bout) {
  const int lane = threadIdx.x;
  const int x = lane >> 3, y = lane & 7;
  const int tr = (y << 3) | x;
  const int chain = blockIdx.x & 511;
  const int b = chain >> 6, n = chain & 63;
  const size_t cbase = ((size_t)b * Tdim) * Ndim + n;
  const float* a_base = A + cbase * 64;
  const float* b_base = Bm + cbase * 8;

  float ea0[16], ea1[16], eb0[16], eb1[16];

  if (blockIdx.x < 512) {
    // ---- forward chain ----
    float* f_base = Fout + cbase * 8;
    float v0 = Z1[n * 8 + y] + b_base[y];
    float q = __expf(v0);                 // y(=j)-indexed, replicated across groups
    float T0 = q; SUM_LO3(T0);
    if (x == 0) f_base[y] = v0 - __logf(T0);
    float sc = __builtin_amdgcn_rcpf(T0);
    fwd_load(a_base, b_base, 1, lane, tr, x, y, ea0, eb0);
#pragma unroll 1
    for (int kk = 0; kk < 64; kk += 2) {
      fwd_load(a_base, b_base, 1 + (kk + 1) * 16, lane, tr, x, y, ea1, eb1);
      fwd_compute(1 + kk * 16, x, y, ea0, eb0, q, sc, f_base);
      if (kk + 2 < 64) fwd_load(a_base, b_base, 1 + (kk + 2) * 16, lane, tr, x, y, ea0, eb0);
      fwd_compute(1 + (kk + 1) * 16, x, y, ea1, eb1, q, sc, f_base);
    }
  } else {
    // ---- backward (beta) chain ----
    float* bo = Bout + cbase * 8;
    float bT = b_base[(size_t)(Tdim - 1) * (Ndim * 8) + x];
    float u = __expf(bT);                 // x(=i)-indexed (beta_{T-1}=0)
    if (x == 0) bo[(size_t)(Tdim - 1) * (Ndim * 8) + y] = 0.f;
    float sc = 1.0f;
    bwd_load(a_base, b_base, Tdim - 1, lane, tr, x, y, ea0, eb0);
#pragma unroll 1
    for (int kk = 0; kk < 64; kk += 2) {
      bwd_load(a_base, b_base, Tdim - 1 - (kk + 1) * 16, lane, tr, x, y, ea1, eb1);
      bwd_compute(Tdim - 1 - kk * 16, x, y, ea0, eb0, u, sc, bo);
      if (kk + 2 < 64) bwd_load(a_base, b_base, Tdim - 1 - (kk + 2) * 16, lane, tr, x, y, ea0, eb0);
      bwd_compute(Tdim - 1 - (kk + 1) * 16, x, y, ea1, eb1, u, sc, bo);
    }
  }
}

// ---------------- kernel 2: gammas (memory-bound, float4 I/O) ----------------
// One lane per (b,t,n,i) row: 8 lanes per g, 8 g's per wave. A row and
// F_prev row loaded as float4x2 (16B/lane, coalesced 2KB/wave), j-sum fully
// in-register, i-sum via 3 DPP stages. g1: per-lane element, DPP group sum.
__global__ __launch_bounds__(256) void gamma_kernel(const float* __restrict__ A,
                                                    const float* __restrict__ Bm,
                                                    const float* __restrict__ F,
                                                    const float* __restrict__ Bo,
                                                    float* __restrict__ G1,
                                                    float* __restrict__ G2) {
  const int lane = threadIdx.x & 63;
  const int i = lane & 7;                               // row index within K
  const int gq = lane >> 3;                             // g within wave (0..7)
  const int g = (blockIdx.x * 4 + (threadIdx.x >> 6)) * 8 + gq;  // flat (b*T+t)*N+n
  const int t = (g >> 6) & (Tdim - 1);

  const float bo_i = Bo[(size_t)g * 8 + i];

  // gamma1: u1 = F+Bo, normalize over the 8-lane group
  {
    float u1 = F[(size_t)g * 8 + i] + bo_i;
    float s1 = __expf(u1);
    SUM_LO3(s1);
    G1[(size_t)g * 8 + i] = u1 - __logf(s1);
  }

  // gamma2
  float4* o = (float4*)&G2[(size_t)g * 64 + i * 8];
  if (t == 0) {
    float4 z = make_float4(0.f, 0.f, 0.f, 0.f);
    o[0] = z; o[1] = z;
  } else {
    const float4* ap = (const float4*)&A[(size_t)g * 64 + i * 8];
    float4 a0 = ap[0], a1 = ap[1];
    const float4* fp = (const float4*)&F[((size_t)g - Ndim) * 8];
    float4 f0 = fp[0], f1 = fp[1];
    float c = bo_i + Bm[(size_t)g * 8 + i];
    float v0 = c + a0.x + f0.x, v1 = c + a0.y + f0.y;
    float v2 = c + a0.z + f0.z, v3 = c + a0.w + f0.w;
    float v4 = c + a1.x + f1.x, v5 = c + a1.y + f1.y;
    float v6 = c + a1.z + f1.z, v7 = c + a1.w + f1.w;
    float r = ((__expf(v0) + __expf(v1)) + (__expf(v2) + __expf(v3)))
            + ((__expf(v4) + __expf(v5)) + (__expf(v6) + __expf(v7)));
    SUM_LO3(r);                                         // sum over i (8-lane group)
    float lq = __logf(r);
    o[0] = make_float4(v0 - lq, v1 - lq, v2 - lq, v3 - lq);
    o[1] = make_float4(v4 - lq, v5 - lq, v6 - lq, v7 - lq);
  }
}

extern "C" void kernel_launch(void* const* d_in, const int* in_sizes, int n_in,
                              void* d_out, int out_size, void* d_ws, size_t ws_size,
                              hipStream_t stream) {
  const float* A  = (const float*)d_in[0];   // (B,T,N,K,K)
  const float* Bm = (const float*)d_in[1];   // (B,T,N,K)
  const float* Z1 = (const float*)d_in[2];   // (N,K)
  float* out = (float*)d_out;
  float* Fout = out;                // forward_probs
  float* Bout = out + FSZ;          // backward_probs
  float* G1   = out + 2 * FSZ;      // gamma1
  float* G2   = out + 3 * FSZ;      // gamma2

  chains_kernel<<<dim3(1024), dim3(64), 0, stream>>>(A, Bm, Z1, Fout, Bout);
  gamma_kernel<<<dim3(8 * Tdim * Ndim / 32), dim3(256), 0, stream>>>(A, Bm, Fout, Bout, G1, G2);
}

// Round 2
// 496.936 us; speedup vs baseline: 1.3790x; 1.0135x over previous
//
#include <hip/hip_runtime.h>

#define Tdim 1024
#define Ndim 64
#define FSZ (8 * 1024 * 64 * 8)

typedef unsigned uint2v __attribute__((ext_vector_type(2)));

// v + dpp(v) at VALU latency. ctrl: 0xB1=quad_perm[1,0,3,2](xor1),
// 0x4E=quad_perm[2,3,0,1](xor2), 0x141=row_half_mirror(xor7),
// 0x128=row_ror:8(xor8).
#define DPPADD(v, ctrl) ((v) + __int_as_float(__builtin_amdgcn_update_dpp( \
    0, __float_as_int(v), ctrl, 0xF, 0xF, false)))

__device__ __forceinline__ float swap_add16(float v) {  // + value from lane^16
  unsigned u = __float_as_uint(v);
  uint2v r = __builtin_amdgcn_permlane16_swap(u, u, false, false);
  return __uint_as_float(r[0]) + __uint_as_float(r[1]);
}
__device__ __forceinline__ float swap_add32(float v) {  // + value from lane^32
  unsigned u = __float_as_uint(v);
  uint2v r = __builtin_amdgcn_permlane32_swap(u, u, false, false);
  return __uint_as_float(r[0]) + __uint_as_float(r[1]);
}

// sum over lane bits {0,1,2}: xor1, xor2, then xor7 (== xor4 after bits 0,1 summed)
#define SUM_LO3(v) { v = DPPADD(v, 0xB1); v = DPPADD(v, 0x4E); v = DPPADD(v, 0x141); }
// sum over lane bits {3,4,5}: xor8 (row_ror:8), xor16, xor32 (permlane swaps)
#define SUM_HI3(v) { v = DPPADD(v, 0x128); v = swap_add16(v); v = swap_add32(v); }

// ---------------- kernel 1: forward + beta recursions ----------------
// One wave per chain (1 wave/SIMD -> zero TLP; all hiding must be ILP).
// Load phase fetches RAW floats only (no exp -> no vmcnt drain inside the
// prefetch); exp is applied at point of use in the compute phase, where it is
// off the serial recurrence. sched_barrier(0) pins load(k+1) above compute(k)
// so the compiler cannot collapse the pipeline to save registers again
// (round-1 pathology: VGPR_Count=56 < 64-float buffer -> pipeline destroyed,
// ~590 cyc/step = exposed memory latency).

__device__ __forceinline__ void fwd_load(const float* __restrict__ a_base,
                                         const float* __restrict__ b_base,
                                         int t0, int lane, int tr, int x, int y,
                                         float (&ra)[16], float (&rb)[16]) {
#pragma unroll
  for (int s = 0; s < 16; ++s) {
    int t = t0 + s; if (t > Tdim - 1) t = Tdim - 1;
    ra[s] = a_base[(size_t)t * (Ndim * 64) + ((s & 1) ? tr : lane)];
    rb[s] = b_base[(size_t)t * (Ndim * 8) + ((s & 1) ? y : x)];
  }
}

__device__ __forceinline__ void fwd_compute(int t0, int x, int y,
                                            const float (&ra)[16], const float (&rb)[16],
                                            float& q, float& sc,
                                            float* __restrict__ f_base) {
#pragma unroll
  for (int s = 0; s < 16; ++s) {
    int t = t0 + s;
    if (t < Tdim) {
      int oidx = (s & 1) ? y : x;                       // output state index role
      float v = __expf(ra[s]) * q;                      // CHAIN (exp off-chain, load-dep only)
      if (!(s & 1)) { SUM_LO3(v); } else { SUM_HI3(v); }  // CHAIN: sum over j (VALU)
      float S = v * (__expf(rb[s]) * sc);               // CHAIN (eb*sc off-chain)
      q = S;
      float T = S;                                      // norm path (parallel)
      if (!(s & 1)) { SUM_HI3(T); } else { SUM_LO3(T); }
      sc = __builtin_amdgcn_rcpf(T);                    // approx ok: scale cancels
      float la = __logf(S) - __logf(T);                 // normalized alpha
      if ((((s & 1) ? x : y)) == 0) f_base[(size_t)t * (Ndim * 8) + oidx] = la;
    }
  }
}

// beta: u_i ~ e^{beta_tau[i] + b_tau[i]} (scaled). r_j = sum_i e^{a_tau[i,j]} u_i.
__device__ __forceinline__ void bwd_load(const float* __restrict__ a_base,
                                         const float* __restrict__ b_base,
                                         int t0, int lane, int tr, int x, int y,
                                         float (&ra)[16], float (&rb)[16]) {
#pragma unroll
  for (int s = 0; s < 16; ++s) {
    int t = t0 - s; if (t < 0) t = 0;
    ra[s] = a_base[(size_t)t * (Ndim * 64) + ((s & 1) ? tr : lane)];
    int tb = t0 - 1 - s; if (tb < 0) tb = 0;            // b at time tau-1
    rb[s] = b_base[(size_t)tb * (Ndim * 8) + ((s & 1) ? x : y)];
  }
}

__device__ __forceinline__ void bwd_compute(int t0, int x, int y,
                                            const float (&ra)[16], const float (&rb)[16],
                                            float& u, float& sc,
                                            float* __restrict__ bo) {
#pragma unroll
  for (int s = 0; s < 16; ++s) {
    int tau = t0 - s;
    if (tau >= 1) {
      float v = __expf(ra[s]) * u;                      // CHAIN
      if (!(s & 1)) { SUM_HI3(v); } else { SUM_LO3(v); }  // CHAIN: sum over i
      int oidx = (s & 1) ? x : y;                       // r's index role
      float unew = (__expf(rb[s]) * sc) * v;            // CHAIN tail
      float W = v;                                      // norm path (parallel)
      if (!(s & 1)) { SUM_LO3(W); } else { SUM_HI3(W); }
      float lb = __logf(v) - __logf(W);
      if ((((s & 1) ? y : x)) == 0) bo[(size_t)(tau - 1) * (Ndim * 8) + oidx] = lb;
      u = unew;
      sc = __builtin_amdgcn_rcpf(W);
    }
  }
}

__global__ __launch_bounds__(64) void chains_kernel(const float* __restrict__ A,
                                                    const float* __restrict__ Bm,
                                                    const float* __restrict__ Z1,
                                                    float* __restrict__ Fout,
                                                    float* __restrict__ Bout) {
  const int lane = threadIdx.x;
  const int x = lane >> 3, y = lane & 7;
  const int tr = (y << 3) | x;
  const int chain = blockIdx.x & 511;
  const int b = chain >> 6, n = chain & 63;
  const size_t cbase = ((size_t)b * Tdim) * Ndim + n;
  const float* a_base = A + cbase * 64;
  const float* b_base = Bm + cbase * 8;

  float ra0[16], ra1[16], rb0[16], rb1[16];

  if (blockIdx.x < 512) {
    // ---- forward chain ----
    float* f_base = Fout + cbase * 8;
    float v0 = Z1[n * 8 + y] + b_base[y];
    float q = __expf(v0);                 // y(=j)-indexed, replicated across groups
    float T0 = q; SUM_LO3(T0);
    if (x == 0) f_base[y] = v0 - __logf(T0);
    float sc = __builtin_amdgcn_rcpf(T0);
    fwd_load(a_base, b_base, 1, lane, tr, x, y, ra0, rb0);
#pragma unroll 1
    for (int kk = 0; kk < 64; kk += 2) {
      fwd_load(a_base, b_base, 1 + (kk + 1) * 16, lane, tr, x, y, ra1, rb1);
      __builtin_amdgcn_sched_barrier(0);
      fwd_compute(1 + kk * 16, x, y, ra0, rb0, q, sc, f_base);
      if (kk + 2 < 64) fwd_load(a_base, b_base, 1 + (kk + 2) * 16, lane, tr, x, y, ra0, rb0);
      __builtin_amdgcn_sched_barrier(0);
      fwd_compute(1 + (kk + 1) * 16, x, y, ra1, rb1, q, sc, f_base);
    }
  } else {
    // ---- backward (beta) chain ----
    float* bo = Bout + cbase * 8;
    float bT = b_base[(size_t)(Tdim - 1) * (Ndim * 8) + x];
    float u = __expf(bT);                 // x(=i)-indexed (beta_{T-1}=0)
    if (x == 0) bo[(size_t)(Tdim - 1) * (Ndim * 8) + y] = 0.f;
    float sc = 1.0f;
    bwd_load(a_base, b_base, Tdim - 1, lane, tr, x, y, ra0, rb0);
#pragma unroll 1
    for (int kk = 0; kk < 64; kk += 2) {
      bwd_load(a_base, b_base, Tdim - 1 - (kk + 1) * 16, lane, tr, x, y, ra1, rb1);
      __builtin_amdgcn_sched_barrier(0);
      bwd_compute(Tdim - 1 - kk * 16, x, y, ra0, rb0, u, sc, bo);
      if (kk + 2 < 64) bwd_load(a_base, b_base, Tdim - 1 - (kk + 2) * 16, lane, tr, x, y, ra0, rb0);
      __builtin_amdgcn_sched_barrier(0);
      bwd_compute(Tdim - 1 - (kk + 1) * 16, x, y, ra1, rb1, u, sc, bo);
    }
  }
}

// ---------------- kernel 2: gammas (memory-bound, float4 I/O) ----------------
// One lane per (b,t,n,i) row: 8 lanes per g, 8 g's per wave. A row and
// F_prev row loaded as float4x2 (16B/lane, coalesced 2KB/wave), j-sum fully
// in-register, i-sum via 3 DPP stages. g1: per-lane element, DPP group sum.
__global__ __launch_bounds__(256) void gamma_kernel(const float* __restrict__ A,
                                                    const float* __restrict__ Bm,
                                                    const float* __restrict__ F,
                                                    const float* __restrict__ Bo,
                                                    float* __restrict__ G1,
                                                    float* __restrict__ G2) {
  const int lane = threadIdx.x & 63;
  const int i = lane & 7;                               // row index within K
  const int gq = lane >> 3;                             // g within wave (0..7)
  const int g = (blockIdx.x * 4 + (threadIdx.x >> 6)) * 8 + gq;  // flat (b*T+t)*N+n
  const int t = (g >> 6) & (Tdim - 1);

  const float bo_i = Bo[(size_t)g * 8 + i];

  // gamma1: u1 = F+Bo, normalize over the 8-lane group
  {
    float u1 = F[(size_t)g * 8 + i] + bo_i;
    float s1 = __expf(u1);
    SUM_LO3(s1);
    G1[(size_t)g * 8 + i] = u1 - __logf(s1);
  }

  // gamma2
  float4* o = (float4*)&G2[(size_t)g * 64 + i * 8];
  if (t == 0) {
    float4 z = make_float4(0.f, 0.f, 0.f, 0.f);
    o[0] = z; o[1] = z;
  } else {
    const float4* ap = (const float4*)&A[(size_t)g * 64 + i * 8];
    float4 a0 = ap[0], a1 = ap[1];
    const float4* fp = (const float4*)&F[((size_t)g - Ndim) * 8];
    float4 f0 = fp[0], f1 = fp[1];
    float c = bo_i + Bm[(size_t)g * 8 + i];
    float v0 = c + a0.x + f0.x, v1 = c + a0.y + f0.y;
    float v2 = c + a0.z + f0.z, v3 = c + a0.w + f0.w;
    float v4 = c + a1.x + f1.x, v5 = c + a1.y + f1.y;
    float v6 = c + a1.z + f1.z, v7 = c + a1.w + f1.w;
    float r = ((__expf(v0) + __expf(v1)) + (__expf(v2) + __expf(v3)))
            + ((__expf(v4) + __expf(v5)) + (__expf(v6) + __expf(v7)));
    SUM_LO3(r);                                         // sum over i (8-lane group)
    float lq = __logf(r);
    o[0] = make_float4(v0 - lq, v1 - lq, v2 - lq, v3 - lq);
    o[1] = make_float4(v4 - lq, v5 - lq, v6 - lq, v7 - lq);
  }
}

extern "C" void kernel_launch(void* const* d_in, const int* in_sizes, int n_in,
                              void* d_out, int out_size, void* d_ws, size_t ws_size,
                              hipStream_t stream) {
  const float* A  = (const float*)d_in[0];   // (B,T,N,K,K)
  const float* Bm = (const float*)d_in[1];   // (B,T,N,K)
  const float* Z1 = (const float*)d_in[2];   // (N,K)
  float* out = (float*)d_out;
  float* Fout = out;                // forward_probs
  float* Bout = out + FSZ;          // backward_probs
  float* G1   = out + 2 * FSZ;      // gamma1
  float* G2   = out + 3 * FSZ;      // gamma2

  chains_kernel<<<dim3(1024), dim3(64), 0, stream>>>(A, Bm, Z1, Fout, Bout);
  gamma_kernel<<<dim3(8 * Tdim * Ndim / 32), dim3(256), 0, stream>>>(A, Bm, Fout, Bout, G1, G2);
}

// Round 3
// 463.814 us; speedup vs baseline: 1.4775x; 1.0714x over previous
//
#include <hip/hip_runtime.h>

#define Tdim 1024
#define Ndim 64
#define FSZ (8 * 1024 * 64 * 8)

typedef unsigned uint2v __attribute__((ext_vector_type(2)));

// v + dpp(v) at VALU latency. ctrl: 0xB1=quad_perm[1,0,3,2](xor1),
// 0x4E=quad_perm[2,3,0,1](xor2), 0x141=row_half_mirror(xor7),
// 0x128=row_ror:8(xor8).
#define DPPADD(v, ctrl) ((v) + __int_as_float(__builtin_amdgcn_update_dpp( \
    0, __float_as_int(v), ctrl, 0xF, 0xF, false)))

__device__ __forceinline__ float swap_add16(float v) {  // + value from lane^16
  unsigned u = __float_as_uint(v);
  uint2v r = __builtin_amdgcn_permlane16_swap(u, u, false, false);
  return __uint_as_float(r[0]) + __uint_as_float(r[1]);
}
__device__ __forceinline__ float swap_add32(float v) {  // + value from lane^32
  unsigned u = __float_as_uint(v);
  uint2v r = __builtin_amdgcn_permlane32_swap(u, u, false, false);
  return __uint_as_float(r[0]) + __uint_as_float(r[1]);
}

// sum over lane bits {0,1,2}: xor1, xor2, then xor7 (== xor4 after bits 0,1 summed)
#define SUM_LO3(v) { v = DPPADD(v, 0xB1); v = DPPADD(v, 0x4E); v = DPPADD(v, 0x141); }
// sum over lane bits {3,4,5}: xor8 (row_ror:8), xor16, xor32 (permlane swaps)
#define SUM_HI3(v) { v = DPPADD(v, 0x128); v = swap_add16(v); v = swap_add32(v); }

// ---------------- kernel 1: forward + beta recursions ----------------
// One wave per chain; grid = 1024 waves = exactly 1/SIMD, so occupancy is
// structurally pinned -> give the wave the whole RF: __launch_bounds__(64,1).
// (Round-2 pathology: default occupancy target capped VGPR at 68 -> the
// 64-float double-buffer was spilled to scratch; every consume was a ~200cy
// scratch reload on the critical path -> 576 cyc/step.)
// Load phase fetches RAW floats; exp applied at point of use (off the serial
// recurrence). sched_barrier(0) pins load(k+1) above compute(k).

__device__ __forceinline__ void fwd_load(const float* __restrict__ a_base,
                                         const float* __restrict__ b_base,
                                         int t0, int lane, int tr, int x, int y,
                                         float (&ra)[16], float (&rb)[16]) {
#pragma unroll
  for (int s = 0; s < 16; ++s) {
    int t = t0 + s; if (t > Tdim - 1) t = Tdim - 1;
    ra[s] = a_base[(size_t)t * (Ndim * 64) + ((s & 1) ? tr : lane)];
    rb[s] = b_base[(size_t)t * (Ndim * 8) + ((s & 1) ? y : x)];
  }
}

__device__ __forceinline__ void fwd_compute(int t0, int x, int y,
                                            const float (&ra)[16], const float (&rb)[16],
                                            float& q, float& sc,
                                            float* __restrict__ f_base) {
#pragma unroll
  for (int s = 0; s < 16; ++s) {
    int t = t0 + s;
    if (t < Tdim) {
      int oidx = (s & 1) ? y : x;                       // output state index role
      float v = __expf(ra[s]) * q;                      // CHAIN (exp off-chain, load-dep only)
      if (!(s & 1)) { SUM_LO3(v); } else { SUM_HI3(v); }  // CHAIN: sum over j (VALU)
      float S = v * (__expf(rb[s]) * sc);               // CHAIN (eb*sc off-chain)
      q = S;
      float T = S;                                      // norm path (parallel)
      if (!(s & 1)) { SUM_HI3(T); } else { SUM_LO3(T); }
      sc = __builtin_amdgcn_rcpf(T);                    // approx ok: scale cancels
      float la = __logf(S * sc);                        // log(S/T), one v_log
      if ((((s & 1) ? x : y)) == 0) f_base[(size_t)t * (Ndim * 8) + oidx] = la;
    }
  }
}

// beta: u_i ~ e^{beta_tau[i] + b_tau[i]} (scaled). r_j = sum_i e^{a_tau[i,j]} u_i.
__device__ __forceinline__ void bwd_load(const float* __restrict__ a_base,
                                         const float* __restrict__ b_base,
                                         int t0, int lane, int tr, int x, int y,
                                         float (&ra)[16], float (&rb)[16]) {
#pragma unroll
  for (int s = 0; s < 16; ++s) {
    int t = t0 - s; if (t < 0) t = 0;
    ra[s] = a_base[(size_t)t * (Ndim * 64) + ((s & 1) ? tr : lane)];
    int tb = t0 - 1 - s; if (tb < 0) tb = 0;            // b at time tau-1
    rb[s] = b_base[(size_t)tb * (Ndim * 8) + ((s & 1) ? x : y)];
  }
}

__device__ __forceinline__ void bwd_compute(int t0, int x, int y,
                                            const float (&ra)[16], const float (&rb)[16],
                                            float& u, float& sc,
                                            float* __restrict__ bo) {
#pragma unroll
  for (int s = 0; s < 16; ++s) {
    int tau = t0 - s;
    if (tau >= 1) {
      float v = __expf(ra[s]) * u;                      // CHAIN
      if (!(s & 1)) { SUM_HI3(v); } else { SUM_LO3(v); }  // CHAIN: sum over i
      int oidx = (s & 1) ? x : y;                       // r's index role
      float unew = (__expf(rb[s]) * sc) * v;            // CHAIN tail
      float W = v;                                      // norm path (parallel)
      if (!(s & 1)) { SUM_LO3(W); } else { SUM_HI3(W); }
      float scn = __builtin_amdgcn_rcpf(W);
      float lb = __logf(v * scn);                       // log(v/W), one v_log
      if ((((s & 1) ? y : x)) == 0) bo[(size_t)(tau - 1) * (Ndim * 8) + oidx] = lb;
      u = unew;
      sc = scn;
    }
  }
}

__global__ __launch_bounds__(64, 1) void chains_kernel(const float* __restrict__ A,
                                                       const float* __restrict__ Bm,
                                                       const float* __restrict__ Z1,
                                                       float* __restrict__ Fout,
                                                       float* __restrict__ Bout) {
  const int lane = threadIdx.x;
  const int x = lane >> 3, y = lane & 7;
  const int tr = (y << 3) | x;
  const int chain = blockIdx.x & 511;
  const int b = chain >> 6, n = chain & 63;
  const size_t cbase = ((size_t)b * Tdim) * Ndim + n;
  const float* a_base = A + cbase * 64;
  const float* b_base = Bm + cbase * 8;

  float ra0[16], ra1[16], rb0[16], rb1[16];

  if (blockIdx.x < 512) {
    // ---- forward chain ----
    float* f_base = Fout + cbase * 8;
    float v0 = Z1[n * 8 + y] + b_base[y];
    float q = __expf(v0);                 // y(=j)-indexed, replicated across groups
    float T0 = q; SUM_LO3(T0);
    if (x == 0) f_base[y] = v0 - __logf(T0);
    float sc = __builtin_amdgcn_rcpf(T0);
    fwd_load(a_base, b_base, 1, lane, tr, x, y, ra0, rb0);
#pragma unroll 1
    for (int kk = 0; kk < 64; kk += 2) {
      fwd_load(a_base, b_base, 1 + (kk + 1) * 16, lane, tr, x, y, ra1, rb1);
      __builtin_amdgcn_sched_barrier(0);
      fwd_compute(1 + kk * 16, x, y, ra0, rb0, q, sc, f_base);
      if (kk + 2 < 64) fwd_load(a_base, b_base, 1 + (kk + 2) * 16, lane, tr, x, y, ra0, rb0);
      __builtin_amdgcn_sched_barrier(0);
      fwd_compute(1 + (kk + 1) * 16, x, y, ra1, rb1, q, sc, f_base);
    }
  } else {
    // ---- backward (beta) chain ----
    float* bo = Bout + cbase * 8;
    float bT = b_base[(size_t)(Tdim - 1) * (Ndim * 8) + x];
    float u = __expf(bT);                 // x(=i)-indexed (beta_{T-1}=0)
    if (x == 0) bo[(size_t)(Tdim - 1) * (Ndim * 8) + y] = 0.f;
    float sc = 1.0f;
    bwd_load(a_base, b_base, Tdim - 1, lane, tr, x, y, ra0, rb0);
#pragma unroll 1
    for (int kk = 0; kk < 64; kk += 2) {
      bwd_load(a_base, b_base, Tdim - 1 - (kk + 1) * 16, lane, tr, x, y, ra1, rb1);
      __builtin_amdgcn_sched_barrier(0);
      bwd_compute(Tdim - 1 - kk * 16, x, y, ra0, rb0, u, sc, bo);
      if (kk + 2 < 64) bwd_load(a_base, b_base, Tdim - 1 - (kk + 2) * 16, lane, tr, x, y, ra0, rb0);
      __builtin_amdgcn_sched_barrier(0);
      bwd_compute(Tdim - 1 - (kk + 1) * 16, x, y, ra1, rb1, u, sc, bo);
    }
  }
}

// ---------------- kernel 2: gammas (memory-bound, float4 I/O) ----------------
// One lane per (b,t,n,i) row: 8 lanes per g, 8 g's per wave. A row and
// F_prev row loaded as float4x2 (16B/lane, coalesced 2KB/wave), j-sum fully
// in-register, i-sum via 3 DPP stages. g1: per-lane element, DPP group sum.
__global__ __launch_bounds__(256) void gamma_kernel(const float* __restrict__ A,
                                                    const float* __restrict__ Bm,
                                                    const float* __restrict__ F,
                                                    const float* __restrict__ Bo,
                                                    float* __restrict__ G1,
                                                    float* __restrict__ G2) {
  const int lane = threadIdx.x & 63;
  const int i = lane & 7;                               // row index within K
  const int gq = lane >> 3;                             // g within wave (0..7)
  const int g = (blockIdx.x * 4 + (threadIdx.x >> 6)) * 8 + gq;  // flat (b*T+t)*N+n
  const int t = (g >> 6) & (Tdim - 1);

  const float bo_i = Bo[(size_t)g * 8 + i];

  // gamma1: u1 = F+Bo, normalize over the 8-lane group
  {
    float u1 = F[(size_t)g * 8 + i] + bo_i;
    float s1 = __expf(u1);
    SUM_LO3(s1);
    G1[(size_t)g * 8 + i] = u1 - __logf(s1);
  }

  // gamma2
  float4* o = (float4*)&G2[(size_t)g * 64 + i * 8];
  if (t == 0) {
    float4 z = make_float4(0.f, 0.f, 0.f, 0.f);
    o[0] = z; o[1] = z;
  } else {
    const float4* ap = (const float4*)&A[(size_t)g * 64 + i * 8];
    float4 a0 = ap[0], a1 = ap[1];
    const float4* fp = (const float4*)&F[((size_t)g - Ndim) * 8];
    float4 f0 = fp[0], f1 = fp[1];
    float c = bo_i + Bm[(size_t)g * 8 + i];
    float v0 = c + a0.x + f0.x, v1 = c + a0.y + f0.y;
    float v2 = c + a0.z + f0.z, v3 = c + a0.w + f0.w;
    float v4 = c + a1.x + f1.x, v5 = c + a1.y + f1.y;
    float v6 = c + a1.z + f1.z, v7 = c + a1.w + f1.w;
    float r = ((__expf(v0) + __expf(v1)) + (__expf(v2) + __expf(v3)))
            + ((__expf(v4) + __expf(v5)) + (__expf(v6) + __expf(v7)));
    SUM_LO3(r);                                         // sum over i (8-lane group)
    float lq = __logf(r);
    o[0] = make_float4(v0 - lq, v1 - lq, v2 - lq, v3 - lq);
    o[1] = make_float4(v4 - lq, v5 - lq, v6 - lq, v7 - lq);
  }
}

extern "C" void kernel_launch(void* const* d_in, const int* in_sizes, int n_in,
                              void* d_out, int out_size, void* d_ws, size_t ws_size,
                              hipStream_t stream) {
  const float* A  = (const float*)d_in[0];   // (B,T,N,K,K)
  const float* Bm = (const float*)d_in[1];   // (B,T,N,K)
  const float* Z1 = (const float*)d_in[2];   // (N,K)
  float* out = (float*)d_out;
  float* Fout = out;                // forward_probs
  float* Bout = out + FSZ;          // backward_probs
  float* G1   = out + 2 * FSZ;      // gamma1
  float* G2   = out + 3 * FSZ;      // gamma2

  chains_kernel<<<dim3(1024), dim3(64), 0, stream>>>(A, Bm, Z1, Fout, Bout);
  gamma_kernel<<<dim3(8 * Tdim * Ndim / 32), dim3(256), 0, stream>>>(A, Bm, Fout, Bout, G1, G2);
}

// Round 4
// 451.846 us; speedup vs baseline: 1.5166x; 1.0265x over previous
//
#include <hip/hip_runtime.h>

#define Tdim 1024
#define Ndim 64
#define FSZ (8 * 1024 * 64 * 8)

typedef unsigned uint2v __attribute__((ext_vector_type(2)));

// v + dpp(v) at VALU latency. ctrl: 0xB1=quad_perm[1,0,3,2](xor1),
// 0x4E=quad_perm[2,3,0,1](xor2), 0x141=row_half_mirror(xor7),
// 0x128=row_ror:8(xor8).
#define DPPADD(v, ctrl) ((v) + __int_as_float(__builtin_amdgcn_update_dpp( \
    0, __float_as_int(v), ctrl, 0xF, 0xF, false)))

__device__ __forceinline__ float swap_add16(float v) {  // + value from lane^16
  unsigned u = __float_as_uint(v);
  uint2v r = __builtin_amdgcn_permlane16_swap(u, u, false, false);
  return __uint_as_float(r[0]) + __uint_as_float(r[1]);
}
__device__ __forceinline__ float swap_add32(float v) {  // + value from lane^32
  unsigned u = __float_as_uint(v);
  uint2v r = __builtin_amdgcn_permlane32_swap(u, u, false, false);
  return __uint_as_float(r[0]) + __uint_as_float(r[1]);
}

// sum over lane bits {0,1,2}: xor1, xor2, then xor7 (== xor4 after bits 0,1 summed)
#define SUM_LO3(v) { v = DPPADD(v, 0xB1); v = DPPADD(v, 0x4E); v = DPPADD(v, 0x141); }
// sum over lane bits {3,4,5}: xor8 (row_ror:8), xor16, xor32 (permlane swaps)
#define SUM_HI3(v) { v = DPPADD(v, 0x128); v = swap_add16(v); v = swap_add32(v); }

// Fire-and-forget global->LDS DMA: LDS dest = uniform base + lane*4,
// global source is per-lane (this is how the XOR swizzle is applied).
#define GLOAD_LDS(gp, lp) __builtin_amdgcn_global_load_lds( \
    (const __attribute__((address_space(1))) unsigned*)(gp), \
    (__attribute__((address_space(3))) unsigned*)(lp), 4, 0, 0)

// ---------------- kernel 1: forward + beta recursions ----------------
// One wave per chain (1/SIMD, zero TLP). Round-3 pathology: a register
// double-buffer needs ~100 live VGPRs; the scheduler insists on a ~68-reg
// schedule and serializes the loads (~5000 stall cyc/batch). Fix: stage
// through LDS with global_load_lds (no VGPR dests, no 64-bit addr temps)
// -> pressure ~40 regs, loads fire-and-forget, waits are counted.
// A is staged XOR-swizzled (LDS word (x,y) holds a[t][x][y^x], applied by
// pre-swizzling the per-lane GLOBAL source): both the identity read
// (word x*8+(y^x)) and the transposed read (word y*8+(x^y)) are bijections
// over 64 words -> 2 lanes/bank -> conflict-free. ds_read latency hidden by
// a depth-4 static-index register ring.

__device__ __forceinline__ void stage_fwd(const float* __restrict__ a_base,
                                          const float* __restrict__ b_base,
                                          int t0, int swz, int lane,
                                          float* sA, float* sB) {
  asm volatile("s_waitcnt lgkmcnt(0)" ::: "memory");  // WAR: prior reads drained (free)
#pragma unroll
  for (int s = 0; s < 16; ++s) {
    int t = t0 + s; if (t > Tdim - 1) t = Tdim - 1;
    GLOAD_LDS(&a_base[(size_t)t * (Ndim * 64) + swz], &sA[s * 64]);
  }
#pragma unroll
  for (int h = 0; h < 2; ++h) {
    int tb = t0 + h * 8 + (lane >> 3); if (tb > Tdim - 1) tb = Tdim - 1;
    GLOAD_LDS(&b_base[(size_t)tb * (Ndim * 8) + (lane & 7)], &sB[h * 64]);
  }
}

__device__ __forceinline__ void stage_bwd(const float* __restrict__ a_base,
                                          const float* __restrict__ b_base,
                                          int t0, int swz, int lane,
                                          float* sA, float* sB) {
  asm volatile("s_waitcnt lgkmcnt(0)" ::: "memory");
#pragma unroll
  for (int s = 0; s < 16; ++s) {
    int t = t0 - s; if (t < 0) t = 0;
    GLOAD_LDS(&a_base[(size_t)t * (Ndim * 64) + swz], &sA[s * 64]);
  }
#pragma unroll
  for (int h = 0; h < 2; ++h) {
    int tb = t0 - 1 - (h * 8 + (lane >> 3)); if (tb < 0) tb = 0;  // b at tau-1
    GLOAD_LDS(&b_base[(size_t)tb * (Ndim * 8) + (lane & 7)], &sB[h * 64]);
  }
}

__device__ __forceinline__ void fwd_compute_lds(int t0, int x, int y, int swz, int trw,
                                                const float* sA, const float* sB,
                                                float& q, float& sc,
                                                float* __restrict__ f_base) {
  float av[4], bv[4];                                  // depth-4 ring, static indices
#pragma unroll
  for (int p = 0; p < 4; ++p) {
    av[p] = sA[p * 64 + ((p & 1) ? trw : swz)];
    bv[p] = sB[p * 8 + ((p & 1) ? y : x)];
  }
#pragma unroll
  for (int s = 0; s < 16; ++s) {
    int t = t0 + s;
    float a = av[s & 3], bb = bv[s & 3];
    if (s + 4 < 16) {                                  // prefetch step s+4 (same parity)
      int p = s + 4;
      av[s & 3] = sA[p * 64 + ((p & 1) ? trw : swz)];
      bv[s & 3] = sB[p * 8 + ((p & 1) ? y : x)];
    }
    if (t < Tdim) {
      int oidx = (s & 1) ? y : x;                      // output state index role
      float v = __expf(a) * q;                         // CHAIN
      if (!(s & 1)) { SUM_LO3(v); } else { SUM_HI3(v); }  // CHAIN: sum over j
      float S = v * (__expf(bb) * sc);                 // CHAIN (eb*sc off-chain)
      q = S;
      float T = S;                                     // norm path (parallel)
      if (!(s & 1)) { SUM_HI3(T); } else { SUM_LO3(T); }
      sc = __builtin_amdgcn_rcpf(T);                   // approx ok: scale cancels
      float la = __logf(S * sc);                       // log(S/T)
      if ((((s & 1) ? x : y)) == 0) f_base[(size_t)t * (Ndim * 8) + oidx] = la;
    }
  }
}

__device__ __forceinline__ void bwd_compute_lds(int t0, int x, int y, int swz, int trw,
                                                const float* sA, const float* sB,
                                                float& u, float& sc,
                                                float* __restrict__ bo) {
  float av[4], bv[4];
#pragma unroll
  for (int p = 0; p < 4; ++p) {
    av[p] = sA[p * 64 + ((p & 1) ? trw : swz)];
    bv[p] = sB[p * 8 + ((p & 1) ? x : y)];
  }
#pragma unroll
  for (int s = 0; s < 16; ++s) {
    int tau = t0 - s;
    float a = av[s & 3], bb = bv[s & 3];
    if (s + 4 < 16) {
      int p = s + 4;
      av[s & 3] = sA[p * 64 + ((p & 1) ? trw : swz)];
      bv[s & 3] = sB[p * 8 + ((p & 1) ? x : y)];
    }
    if (tau >= 1) {
      float v = __expf(a) * u;                         // CHAIN
      if (!(s & 1)) { SUM_HI3(v); } else { SUM_LO3(v); }  // CHAIN: sum over i
      int oidx = (s & 1) ? x : y;                      // r's index role
      float unew = (__expf(bb) * sc) * v;              // CHAIN tail
      float W = v;                                     // norm path (parallel)
      if (!(s & 1)) { SUM_LO3(W); } else { SUM_HI3(W); }
      float scn = __builtin_amdgcn_rcpf(W);
      float lb = __logf(v * scn);                      // log(v/W)
      if ((((s & 1) ? y : x)) == 0) bo[(size_t)(tau - 1) * (Ndim * 8) + oidx] = lb;
      u = unew;
      sc = scn;
    }
  }
}

__global__ __launch_bounds__(64, 1) void chains_kernel(const float* __restrict__ A,
                                                       const float* __restrict__ Bm,
                                                       const float* __restrict__ Z1,
                                                       float* __restrict__ Fout,
                                                       float* __restrict__ Bout) {
  // Separate __shared__ objects -> distinct alias sets -> counted vmcnt, not vmcnt(0).
  __shared__ float sA0[1024], sA1[1024], sB0[128], sB1[128];
  const int lane = threadIdx.x;
  const int x = lane >> 3, y = lane & 7;
  const int swz = (x << 3) | (y ^ x);   // staging source index == identity-read word
  const int trw = (y << 3) | (x ^ y);   // transpose-read word
  const int chain = blockIdx.x & 511;
  const int b = chain >> 6, n = chain & 63;
  const size_t cbase = ((size_t)b * Tdim) * Ndim + n;
  const float* a_base = A + cbase * 64;
  const float* b_base = Bm + cbase * 8;

  if (blockIdx.x < 512) {
    // ---- forward chain ----
    float* f_base = Fout + cbase * 8;
    float v0 = Z1[n * 8 + y] + b_base[y];
    float q = __expf(v0);                 // y(=j)-indexed, replicated across groups
    float T0 = q; SUM_LO3(T0);
    if (x == 0) f_base[y] = v0 - __logf(T0);
    float sc = __builtin_amdgcn_rcpf(T0);
    stage_fwd(a_base, b_base, 1, swz, lane, sA0, sB0);
#pragma unroll 1
    for (int kk = 0; kk < 64; kk += 2) {
      stage_fwd(a_base, b_base, 1 + (kk + 1) * 16, swz, lane, sA1, sB1);
      fwd_compute_lds(1 + kk * 16, x, y, swz, trw, sA0, sB0, q, sc, f_base);
      if (kk + 2 < 64) stage_fwd(a_base, b_base, 1 + (kk + 2) * 16, swz, lane, sA0, sB0);
      fwd_compute_lds(1 + (kk + 1) * 16, x, y, swz, trw, sA1, sB1, q, sc, f_base);
    }
  } else {
    // ---- backward (beta) chain ----
    float* bo = Bout + cbase * 8;
    float bT = b_base[(size_t)(Tdim - 1) * (Ndim * 8) + x];
    float u = __expf(bT);                 // x(=i)-indexed (beta_{T-1}=0)
    if (x == 0) bo[(size_t)(Tdim - 1) * (Ndim * 8) + y] = 0.f;
    float sc = 1.0f;
    stage_bwd(a_base, b_base, Tdim - 1, swz, lane, sA0, sB0);
#pragma unroll 1
    for (int kk = 0; kk < 64; kk += 2) {
      stage_bwd(a_base, b_base, Tdim - 1 - (kk + 1) * 16, swz, lane, sA1, sB1);
      bwd_compute_lds(Tdim - 1 - kk * 16, x, y, swz, trw, sA0, sB0, u, sc, bo);
      if (kk + 2 < 64) stage_bwd(a_base, b_base, Tdim - 1 - (kk + 2) * 16, swz, lane, sA0, sB0);
      bwd_compute_lds(Tdim - 1 - (kk + 1) * 16, x, y, swz, trw, sA1, sB1, u, sc, bo);
    }
  }
}

// ---------------- kernel 2: gammas (memory-bound, float4 I/O) ----------------
// One lane per (b,t,n,i) row: 8 lanes per g, 8 g's per wave. A row and
// F_prev row loaded as float4x2 (16B/lane, coalesced 2KB/wave), j-sum fully
// in-register, i-sum via 3 DPP stages. g1: per-lane element, DPP group sum.
__global__ __launch_bounds__(256) void gamma_kernel(const float* __restrict__ A,
                                                    const float* __restrict__ Bm,
                                                    const float* __restrict__ F,
                                                    const float* __restrict__ Bo,
                                                    float* __restrict__ G1,
                                                    float* __restrict__ G2) {
  const int lane = threadIdx.x & 63;
  const int i = lane & 7;                               // row index within K
  const int gq = lane >> 3;                             // g within wave (0..7)
  const int g = (blockIdx.x * 4 + (threadIdx.x >> 6)) * 8 + gq;  // flat (b*T+t)*N+n
  const int t = (g >> 6) & (Tdim - 1);

  const float bo_i = Bo[(size_t)g * 8 + i];

  // gamma1: u1 = F+Bo, normalize over the 8-lane group
  {
    float u1 = F[(size_t)g * 8 + i] + bo_i;
    float s1 = __expf(u1);
    SUM_LO3(s1);
    G1[(size_t)g * 8 + i] = u1 - __logf(s1);
  }

  // gamma2
  float4* o = (float4*)&G2[(size_t)g * 64 + i * 8];
  if (t == 0) {
    float4 z = make_float4(0.f, 0.f, 0.f, 0.f);
    o[0] = z; o[1] = z;
  } else {
    const float4* ap = (const float4*)&A[(size_t)g * 64 + i * 8];
    float4 a0 = ap[0], a1 = ap[1];
    const float4* fp = (const float4*)&F[((size_t)g - Ndim) * 8];
    float4 f0 = fp[0], f1 = fp[1];
    float c = bo_i + Bm[(size_t)g * 8 + i];
    float v0 = c + a0.x + f0.x, v1 = c + a0.y + f0.y;
    float v2 = c + a0.z + f0.z, v3 = c + a0.w + f0.w;
    float v4 = c + a1.x + f1.x, v5 = c + a1.y + f1.y;
    float v6 = c + a1.z + f1.z, v7 = c + a1.w + f1.w;
    float r = ((__expf(v0) + __expf(v1)) + (__expf(v2) + __expf(v3)))
            + ((__expf(v4) + __expf(v5)) + (__expf(v6) + __expf(v7)));
    SUM_LO3(r);                                         // sum over i (8-lane group)
    float lq = __logf(r);
    o[0] = make_float4(v0 - lq, v1 - lq, v2 - lq, v3 - lq);
    o[1] = make_float4(v4 - lq, v5 - lq, v6 - lq, v7 - lq);
  }
}

extern "C" void kernel_launch(void* const* d_in, const int* in_sizes, int n_in,
                              void* d_out, int out_size, void* d_ws, size_t ws_size,
                              hipStream_t stream) {
  const float* A  = (const float*)d_in[0];   // (B,T,N,K,K)
  const float* Bm = (const float*)d_in[1];   // (B,T,N,K)
  const float* Z1 = (const float*)d_in[2];   // (N,K)
  float* out = (float*)d_out;
  float* Fout = out;                // forward_probs
  float* Bout = out + FSZ;          // backward_probs
  float* G1   = out + 2 * FSZ;      // gamma1
  float* G2   = out + 3 * FSZ;      // gamma2

  chains_kernel<<<dim3(1024), dim3(64), 0, stream>>>(A, Bm, Z1, Fout, Bout);
  gamma_kernel<<<dim3(8 * Tdim * Ndim / 32), dim3(256), 0, stream>>>(A, Bm, Fout, Bout, G1, G2);
}